// Round 9
// baseline (711.441 us; speedup 1.0000x reference)
//
#include <hip/hip_runtime.h>
#include <math.h>

// Problem constants
#define T_  256
#define B_  128
#define OBS_ 256
#define H_  512
#define E_  1024
#define DS_ 16
#define DC_ 4
#define DR_ 32
#define M_  (T_*B_)   // 32768 flattened (t,b) rows

typedef unsigned short u16;
typedef short short8 __attribute__((ext_vector_type(8)));   // 8 bf16 (4 VGPRs)
typedef unsigned short ushort8 __attribute__((ext_vector_type(8)));
typedef float f32x4  __attribute__((ext_vector_type(4)));

__device__ __forceinline__ float sigmoidf_(float v){ return 1.f/(1.f+__expf(-v)); }

__device__ __forceinline__ float b2f(u16 h){
  unsigned int x = ((unsigned int)h) << 16; float f;
  __builtin_memcpy(&f, &x, 4); return f;
}
__device__ __forceinline__ u16 f2b(float f){
  unsigned int x; __builtin_memcpy(&x, &f, 4);
  unsigned int lsb = (x >> 16) & 1u;
  x += 0x7fffu + lsb;            // RNE
  return (u16)(x >> 16);
}
__device__ __forceinline__ void ld4(const float* p, float v[4]){
  const float4 t = *(const float4*)p; v[0]=t.x; v[1]=t.y; v[2]=t.z; v[3]=t.w;
}
__device__ __forceinline__ void st4(u16* p, const float v[4]){
  ushort4 t; t.x=f2b(v[0]); t.y=f2b(v[1]); t.z=f2b(v[2]); t.w=f2b(v[3]);
  *(ushort4*)p = t;
}
__device__ __forceinline__ void store1(float* p, float v){ *p = v; }
__device__ __forceinline__ void store1(u16* p,  float v){ *p = f2b(v); }
__device__ __forceinline__ void store1(_Float16* p, float v){ *p = (_Float16)v; }

// async global->LDS, 16B per lane. LDS dest = wave-uniform base + lane*16.
__device__ __forceinline__ void gl_lds16(const u16* g, u16* l){
  __builtin_amdgcn_global_load_lds(
      (const __attribute__((address_space(1))) void*)g,
      (__attribute__((address_space(3))) void*)l, 16, 0, 0);
}

// All 7 weight tensors in one launch. Sizes in 1024-element chunks:
// enc 128 | in 1024 | xp 64 | out 512 | w1 256 | w2 256 | wdt 32 => 2272 blocks
__global__ __launch_bounds__(256) void cvt_weights(
    const float* __restrict__ w_enc, const float* __restrict__ w_in,
    const float* __restrict__ w_xp,  const float* __restrict__ w_out,
    const float* __restrict__ w1,    const float* __restrict__ w2,
    const float* __restrict__ w_dt,
    u16* o_enc, u16* o_in, u16* o_xp, u16* o_out, u16* o1, u16* o2, u16* o_dt)
{
  const int blk = blockIdx.x;
  const float* src; u16* dst; int base;
  if      (blk < 128)  { src=w_enc; dst=o_enc; base=blk; }
  else if (blk < 1152) { src=w_in;  dst=o_in;  base=blk-128; }
  else if (blk < 1216) { src=w_xp;  dst=o_xp;  base=blk-1152; }
  else if (blk < 1728) { src=w_out; dst=o_out; base=blk-1216; }
  else if (blk < 1984) { src=w1;    dst=o1;    base=blk-1728; }
  else if (blk < 2240) { src=w2;    dst=o2;    base=blk-1984; }
  else                 { src=w_dt;  dst=o_dt;  base=blk-2240; }
  const int i = base*1024 + threadIdx.x*4;
  float v[4]; ld4(src+i, v); st4(dst+i, v);
}

// ---------------------------------------------------------------------------
// MFMA bf16 GEMM (m97 structure): C = A @ B^T, 256 thr = 4 waves, each wave
// 64x64 via 4x4 mfma_f32_16x16x32_bf16, global_load_lds staging.
// BK in {32,64}: BK=64 halves barrier-drain count (32 MFMA per barrier) at
// 32 KB LDS — stays clear of the BK=128 occupancy cliff (guide m132).
// Staging LDS offset c*2048 + tid*8 holds for any BK ((t/CPR)*BK+(t%CPR)*8
// == t*8 with CPR=BK/8); fragments gain a ks-subloop.
// EP: 0 none, 1 bias+relu, 2 bias+softplus (fp16 out), 3 +bf16 residual,
//     4 bias only, 6 fp32 store + bf16 aux copy of cols<32
// ---------------------------------------------------------------------------
template<int EP, typename TC, int BM, int BN, int BK>
__global__ __launch_bounds__(256) void mgemm(
    const u16* __restrict__ A, int lda,
    const u16* __restrict__ Bm, int ldb,
    TC* __restrict__ C, int ldc, int K,
    const float* __restrict__ bias,
    const u16* __restrict__ add,
    u16* __restrict__ aux)
{
  constexpr int WC  = BN/64;              // wave cols (BM/64 * BN/64 == 4)
  constexpr int CPR = BK/8;               // 8-elt chunks per row
  constexpr int RPC = 256/CPR;            // rows covered per gl_lds16 call
  constexpr int NKS = BK/32;              // 32-K substeps per iteration
  __shared__ __align__(16) u16 sm[(BM+BN)*BK];
  u16* sA = sm;
  u16* sB = sm + BM*BK;
  const int tid  = threadIdx.x;
  const int bm = blockIdx.x * BM, bn = blockIdx.y * BN;
  const int w = tid >> 6, lane = tid & 63;
  const int wr = (WC==1) ? w : (w >> 1);
  const int wc = (WC==1) ? 0 : (w & 1);
  const int ln = lane & 15, q = lane >> 4;

  const u16* Ag = A  + (size_t)(bm + tid/CPR)*lda + (tid%CPR)*8;
  const u16* Bg = Bm + (size_t)(bn + tid/CPR)*ldb + (tid%CPR)*8;
  const int arow = wr*64 + ln;
  const int brow = wc*64 + ln;

  f32x4 acc[4][4] = {};
  for (int k0 = 0; k0 < K; k0 += BK){
#pragma unroll
    for (int c = 0; c < BM/RPC; ++c)
      gl_lds16(Ag + (size_t)(c*RPC)*lda + k0, sA + c*2048 + tid*8);
#pragma unroll
    for (int c = 0; c < BN/RPC; ++c)
      gl_lds16(Bg + (size_t)(c*RPC)*ldb + k0, sB + c*2048 + tid*8);
    __syncthreads();
    short8 af[NKS][4], bf[NKS][4];
#pragma unroll
    for (int ks=0;ks<NKS;ks++){
#pragma unroll
      for (int i=0;i<4;i++) af[ks][i] = *(const short8*)&sA[(arow + i*16)*BK + ks*32 + q*8];
#pragma unroll
      for (int j=0;j<4;j++) bf[ks][j] = *(const short8*)&sB[(brow + j*16)*BK + ks*32 + q*8];
    }
#pragma unroll
    for (int ks=0;ks<NKS;ks++)
#pragma unroll
      for (int i=0;i<4;i++)
#pragma unroll
        for (int j=0;j<4;j++)
          acc[i][j] = __builtin_amdgcn_mfma_f32_16x16x32_bf16(af[ks][i], bf[ks][j], acc[i][j], 0,0,0);
    __syncthreads();
  }
#pragma unroll
  for (int i=0;i<4;i++){
#pragma unroll
    for (int r=0;r<4;r++){
      const size_t row = (size_t)(bm + wr*64 + i*16 + q*4 + r);
#pragma unroll
      for (int j=0;j<4;j++){
        const int col = bn + wc*64 + j*16 + ln;
        float t = acc[i][j][r];
        if (EP==1 || EP==4) t += bias[col];
        if (EP==2){ t += bias[col];
                    t = fmaxf(t,0.f) + __logf(1.f + __expf(-fabsf(t))); }
        if (EP==1) t = fmaxf(t, 0.f);
        if (EP==3) t += b2f(add[row*(size_t)ldc + col]);
        store1(&C[row*(size_t)ldc + col], t);
        if (EP==6 && col < 32) aux[row*32 + col] = f2b(t);
      }
    }
  }
}

// ---------------------------------------------------------------------------
// Encoder GEMM with FUSED fp32->bf16 A-conversion: feats = relu(x @ Wenc^T
// + b_enc). A staged via registers (2x float4 load -> 8x f2b -> ds_write),
// producing the SAME LDS layout gl_lds16 would; B async-staged. Verified
// round 8; unchanged.
// ---------------------------------------------------------------------------
__global__ __launch_bounds__(256) void mgemm_enc(
    const float* __restrict__ A,        // fp32 [M][OBS]
    const u16* __restrict__ Bm,         // bf16 [H][OBS]
    u16* __restrict__ C,                // bf16 [M][H]
    const float* __restrict__ bias)
{
  __shared__ __align__(16) u16 sm[(128+128)*32];
  u16* sA = sm;
  u16* sB = sm + 128*32;
  const int tid  = threadIdx.x;
  const int bm = blockIdx.x * 128, bn = blockIdx.y * 128;
  const int w = tid >> 6, lane = tid & 63;
  const int wr = w >> 1, wc = w & 1;
  const int ln = lane & 15, q = lane >> 4;

  const float* Ag = A  + (size_t)(bm + (tid>>2))*OBS_ + ((tid&3)<<3);
  const u16*   Bg = Bm + (size_t)(bn + (tid>>2))*OBS_ + ((tid&3)<<3);
  const int arow = wr*64 + ln;
  const int brow = wc*64 + ln;

  f32x4 acc[4][4] = {};
  for (int k0 = 0; k0 < OBS_; k0 += 32){
#pragma unroll
    for (int c = 0; c < 2; ++c){
      const float* src = Ag + (size_t)(c*64)*OBS_ + k0;
      const float4 v0 = *(const float4*)(src);
      const float4 v1 = *(const float4*)(src + 4);
      ushort8 o;
      o[0]=f2b(v0.x); o[1]=f2b(v0.y); o[2]=f2b(v0.z); o[3]=f2b(v0.w);
      o[4]=f2b(v1.x); o[5]=f2b(v1.y); o[6]=f2b(v1.z); o[7]=f2b(v1.w);
      *(ushort8*)&sA[c*2048 + tid*8] = o;
    }
#pragma unroll
    for (int c = 0; c < 2; ++c)
      gl_lds16(Bg + (size_t)(c*64)*OBS_ + k0, sB + c*2048 + tid*8);
    __syncthreads();
    short8 af[4], bf[4];
#pragma unroll
    for (int i=0;i<4;i++) af[i] = *(const short8*)&sA[(arow + i*16)*32 + q*8];
#pragma unroll
    for (int j=0;j<4;j++) bf[j] = *(const short8*)&sB[(brow + j*16)*32 + q*8];
#pragma unroll
    for (int i=0;i<4;i++)
#pragma unroll
      for (int j=0;j<4;j++)
        acc[i][j] = __builtin_amdgcn_mfma_f32_16x16x32_bf16(af[i], bf[j], acc[i][j], 0,0,0);
    __syncthreads();
  }
#pragma unroll
  for (int i=0;i<4;i++){
#pragma unroll
    for (int r=0;r<4;r++){
      const size_t row = (size_t)(bm + wr*64 + i*16 + q*4 + r);
#pragma unroll
      for (int j=0;j<4;j++){
        const int col = bn + wc*64 + j*16 + ln;
        float t = acc[i][j][r] + bias[col];
        C[row*(size_t)H_ + col] = f2b(fmaxf(t, 0.f));
      }
    }
  }
}

// xc[t,b,e] = silu( sum_j conv_w[e,j] * masked_src(t-3+j) + conv_b[e] )
// Vectorized x8: each thread does 8 consecutive e (G13). Block is t-uniform
// (t = g>>14), so the t<3 conv_state path has no divergence.
__global__ __launch_bounds__(256) void conv_kernel(
    const u16* __restrict__ xr, const float* __restrict__ conv_state,
    const int* __restrict__ dones,
    const float* __restrict__ conv_w, const float* __restrict__ conv_b,
    u16* __restrict__ xc)
{
  const int g = blockIdx.x * 256 + threadIdx.x;   // over T*B*E/8
  const int e8   = g & 127;                       // E_/8 = 128
  const int rest = g >> 7;
  const int b = rest & (B_-1);
  const int t = rest >> 7;
  const int e0 = e8 * 8;

  float wv[8][4];
#pragma unroll
  for (int j=0;j<8;j++) ld4(conv_w + (e0+j)*4, wv[j]);
  float bias[8];
  { float v[4]; ld4(conv_b + e0,     v); bias[0]=v[0];bias[1]=v[1];bias[2]=v[2];bias[3]=v[3];
    ld4(conv_b + e0 + 4, v); bias[4]=v[0];bias[5]=v[1];bias[6]=v[2];bias[7]=v[3]; }

  float csv[8][4];
  if (t < 3){
#pragma unroll
    for (int j=0;j<8;j++) ld4(conv_state + ((size_t)(b*E_+e0+j))*4, csv[j]);
  }

  const size_t row = ((size_t)(t*B_+b))*E_ + e0;
  const ushort8 x3 = *(const ushort8*)&xr[row];
  float val[8];
#pragma unroll
  for (int j=0;j<8;j++) val[j] = wv[j][3] * b2f(x3[j]);

  float m = 1.f;
  if (t >= 1){
    m *= 1.f - (float)dones[(t-1)*B_+b];
    const ushort8 xv = *(const ushort8*)&xr[row - (size_t)B_*E_];
#pragma unroll
    for (int j=0;j<8;j++) val[j] = fmaf(wv[j][2], m*b2f(xv[j]), val[j]);
  } else {
#pragma unroll
    for (int j=0;j<8;j++) val[j] = fmaf(wv[j][2], csv[j][3], val[j]);
  }
  if (t >= 2){
    m *= 1.f - (float)dones[(t-2)*B_+b];
    const ushort8 xv = *(const ushort8*)&xr[row - (size_t)2*B_*E_];
#pragma unroll
    for (int j=0;j<8;j++) val[j] = fmaf(wv[j][1], m*b2f(xv[j]), val[j]);
  } else {
#pragma unroll
    for (int j=0;j<8;j++) val[j] = fmaf(wv[j][1], m*csv[j][t-2+4], val[j]);
  }
  if (t >= 3){
    m *= 1.f - (float)dones[(t-3)*B_+b];
    const ushort8 xv = *(const ushort8*)&xr[row - (size_t)3*B_*E_];
#pragma unroll
    for (int j=0;j<8;j++) val[j] = fmaf(wv[j][0], m*b2f(xv[j]), val[j]);
  } else {
#pragma unroll
    for (int j=0;j<8;j++) val[j] = fmaf(wv[j][0], m*csv[j][t-3+4], val[j]);
  }

  ushort8 o;
#pragma unroll
  for (int j=0;j<8;j++){
    const float v = val[j] + bias[j];
    o[j] = f2b(v * sigmoidf_(v));   // silu
  }
  *(ushort8*)&xc[((size_t)(t*B_+b))*E_ + e0] = o;
}

// ---------------------------------------------------------------------------
// SSM scan (round-2 form, FROZEN — rounds 3-7 all regressed perturbations).
// dt PRE-COMPUTED by MFMA GEMM (softplus, fp16) in a stride-E_ buffer; z/g
// in a stride-E_ buffer. Per t: 8 uniform float4 B/C loads (SGPR s_load
// pipeline — do not perturb), dtv/xcv/zv/done streams, closed-form dA
// (1 exp + 15 muls) with mask folded into q. Byte-identical to round 2.
// ---------------------------------------------------------------------------
template<bool ST>
__device__ __forceinline__ void scan_loop(
    const float4* rp, const _Float16* dtp, const u16* xcp, u16* zp,
    const int* dp, float* s, const float* Ae, float c, float Dv)
{
  float mprev = 1.f;
#pragma unroll 2
  for (int t=0;t<T_;t++){
    float4 r[8];
#pragma unroll
    for (int i=0;i<8;i++) r[i] = rp[i];
    const float dtv = (float)dtp[0];
    const float xcv = b2f(*xcp);
    const float zv  = b2f(*zp);
    const int   dn  = *dp;

    float Bv[16], Cv[16];
#pragma unroll
    for (int i=0;i<4;i++){
      Bv[4*i+0]=r[i].x;   Bv[4*i+1]=r[i].y;   Bv[4*i+2]=r[i].z;   Bv[4*i+3]=r[i].w;
      Cv[4*i+0]=r[4+i].x; Cv[4*i+1]=r[4+i].y; Cv[4*i+2]=r[4+i].z; Cv[4*i+3]=r[4+i].w;
    }
    const float xdt = xcv * dtv;

    float p[16];
    if (ST){
      // dA[n] = q^(n+1), q = exp(dtv*A[e,0]); carry-mask folded into q.
      const float q = __expf(dtv * c) * mprev;
      const float q2 = q*q;
      const float q4 = q2*q2;
      const float q8 = q4*q4;
      p[0]=q;     p[1]=q2;    p[2]=q2*q;  p[3]=q4;
      p[4]=q4*q;  p[5]=q4*q2; p[6]=q4*p[2]; p[7]=q8;
      p[8]=q8*q;  p[9]=q8*q2; p[10]=q8*p[2]; p[11]=q8*q4;
      p[12]=q8*p[4]; p[13]=q8*p[5]; p[14]=q8*p[6]; p[15]=q8*q8;
    } else {
#pragma unroll
      for (int n=0;n<DS_;n++) p[n] = __expf(dtv * Ae[n]) * mprev;
    }

    float y0 = Dv * xcv, y1 = 0.f;
#pragma unroll
    for (int n=0;n<DS_;n++){
      s[n] = fmaf(s[n], p[n], xdt * Bv[n]);
      if (n & 1) y1 = fmaf(s[n], Cv[n], y1);
      else       y0 = fmaf(s[n], Cv[n], y0);
    }
    mprev = dn ? 0.f : 1.f;
    *zp = f2b((y0+y1) * zv * sigmoidf_(zv));     // g = y * silu(z)

    rp  += (size_t)B_*16;          // xdb rows are 16 float4 wide
    dtp += (size_t)B_*E_;
    xcp += (size_t)B_*E_;
    zp  += (size_t)B_*E_;
    dp  += B_;
  }
}

__global__ __launch_bounds__(256, 2) void scan_kernel(
    const u16* __restrict__ xc, const float* __restrict__ xdb,
    const _Float16* __restrict__ dt,
    u16* __restrict__ zg,
    const int* __restrict__ dones,
    const float* __restrict__ ssm_state, const float* __restrict__ A_log,
    const float* __restrict__ Dvec)
{
  const int e = blockIdx.x * 256 + threadIdx.x;  // grid.x = E_/256
  const int b = blockIdx.y;
  float Ae[DS_], s[DS_];
#pragma unroll
  for (int n=0;n<DS_;n++){
    Ae[n] = -expf(A_log[e*DS_+n]);
    s[n]  = ssm_state[((size_t)(b*E_+e))*DS_ + n];
  }
  const float c = Ae[0];
  bool st = true;
#pragma unroll
  for (int n=1;n<DS_;n++)
    st = st && (fabsf(Ae[n] - (float)(n+1)*c) <= 1e-5f*(float)(n+1)*fabsf(c));
  const float Dv = Dvec[e];

  const float4*    rp  = (const float4*)xdb + (size_t)b*16 + 8;  // cols 32..63
  const _Float16*  dtp = dt + (size_t)b*E_ + e;
  const u16*       xcp = xc + (size_t)b*E_ + e;
  u16*             zp  = zg + (size_t)b*E_ + e;
  const int*       dp  = dones + b;

  if (st) scan_loop<true >(rp, dtp, xcp, zp, dp, s, Ae, c, Dv);
  else    scan_loop<false>(rp, dtp, xcp, zp, dp, s, Ae, c, Dv);
}

// In-place LayerNorm over rows of length 512 (fp32).
__global__ __launch_bounds__(256) void ln_kernel(
    float* __restrict__ h, const float* __restrict__ gamma, const float* __restrict__ beta)
{
  const int row = blockIdx.x;
  const int tid = threadIdx.x;
  float* p = h + (size_t)row * H_;
  const float v0 = p[tid], v1 = p[tid+256];
  float sum = v0 + v1, sq = v0*v0 + v1*v1;
#pragma unroll
  for (int o=32;o>0;o>>=1){ sum += __shfl_down(sum,o); sq += __shfl_down(sq,o); }
  __shared__ float ss[4], qq[4], mv[2];
  const int wid = tid >> 6;
  if ((tid & 63) == 0){ ss[wid]=sum; qq[wid]=sq; }
  __syncthreads();
  if (tid == 0){
    const float st = ss[0]+ss[1]+ss[2]+ss[3];
    const float qt = qq[0]+qq[1]+qq[2]+qq[3];
    const float mu = st * (1.f/H_);
    const float var = qt * (1.f/H_) - mu*mu;
    mv[0] = mu; mv[1] = rsqrtf(var + 1e-5f);
  }
  __syncthreads();
  const float mu = mv[0], r = mv[1];
  p[tid]     = (v0-mu)*r*gamma[tid]     + beta[tid];
  p[tid+256] = (v1-mu)*r*gamma[tid+256] + beta[tid+256];
}

extern "C" void kernel_launch(void* const* d_in, const int* in_sizes, int n_in,
                              void* d_out, int out_size, void* d_ws, size_t ws_size,
                              hipStream_t stream)
{
  const float* x          = (const float*)d_in[0];
  const int*   dones      = (const int*)  d_in[1];
  const float* conv_state = (const float*)d_in[2];
  const float* ssm_state  = (const float*)d_in[3];
  const float* W_enc      = (const float*)d_in[4];
  const float* b_enc      = (const float*)d_in[5];
  const float* W_in       = (const float*)d_in[6];
  const float* conv_w     = (const float*)d_in[7];
  const float* conv_b     = (const float*)d_in[8];
  const float* W_xproj    = (const float*)d_in[9];
  const float* W_dt       = (const float*)d_in[10];
  const float* b_dt       = (const float*)d_in[11];
  const float* A_log      = (const float*)d_in[12];
  const float* Dv         = (const float*)d_in[13];
  const float* W_out      = (const float*)d_in[14];
  const float* W1         = (const float*)d_in[15];
  const float* b1         = (const float*)d_in[16];
  const float* W2         = (const float*)d_in[17];
  const float* b2         = (const float*)d_in[18];
  const float* gamma      = (const float*)d_in[19];
  const float* beta       = (const float*)d_in[20];

  // Workspace layout IDENTICAL to known-good 205,914,112-byte footprint
  // (round-8 configuration):
  //  R0: xr bf16 (step 2-3) -> dt fp16 (5-6) -> h1 bf16 (8-9)
  //  R1: z bf16 (2-6) -> g (6-7)
  //  R2: xc (3-6) -> h bf16 (7-8)
  //  d_out (64 MiB): feats bf16 [0,32Mi) (1-7); xdb f32 @32Mi (4-6);
  //    xdb32 bf16 @40Mi (4-5); wdtb bf16 @44Mi (0-5); h2 fp32 + LN (9-10)
  char* w = (char*)d_ws;
  u16*   xr   = (u16*)(w + 0);
  _Float16* dt = (_Float16*)(w + 0);
  u16*   h1   = (u16*)(w + 0);
  u16*   zg   = (u16*)(w + 67108864);
  u16*   xc   = (u16*)(w + 134217728);
  u16*   h    = (u16*)(w + 134217728);
  u16*   wenc = (u16*)(w + 201326592);
  u16*   win  = wenc + 131072;
  u16*   wxp  = win  + 1048576;
  u16*   wout = wxp  + 65536;
  u16*   w1b  = wout + 524288;
  u16*   w2b  = w1b  + 262144;
  u16*   feats = (u16*)d_out;
  float* xdbf  = (float*)((char*)d_out + 33554432);   // M x 64 fp32 (8.4 MB)
  u16*   xdb32 = (u16*)  ((char*)d_out + 41943040);   // M x 32 bf16 (2.1 MB)
  u16*   wdtb  = (u16*)  ((char*)d_out + 46137344);   // E x 32 bf16 (64 KiB)
  float* out   = (float*)d_out;

  const dim3 blk(256);

  // 0. weight fp32 -> bf16 conversion
  cvt_weights<<<dim3(2272), blk, 0, stream>>>(W_enc, W_in, W_xproj, W_out, W1, W2, W_dt,
                                              wenc, win, wxp, wout, w1b, w2b, wdtb);

  // 1. feats = relu(x @ W_enc^T + b_enc), fused fp32->bf16 A-staging -> d_out
  mgemm_enc<<<dim3(M_/128, H_/128), blk, 0, stream>>>(x, wenc, feats, b_enc);
  // 2a. xr = feats @ W_in[:E]^T                    -> R0 (bf16), BK=64
  mgemm<0,u16,128,128,64><<<dim3(M_/128, E_/128), blk, 0, stream>>>(feats, H_, win, H_, xr, E_, H_, nullptr, nullptr, nullptr);
  // 2b. z = feats @ W_in[E:]^T                     -> R1 (bf16), BK=64
  mgemm<0,u16,128,128,64><<<dim3(M_/128, E_/128), blk, 0, stream>>>(feats, H_, win + (size_t)E_*H_, H_, zg, E_, H_, nullptr, nullptr, nullptr);
  // 3. masked causal conv + silu                   -> xc (bf16, R2)
  conv_kernel<<<dim3((M_*E_)/(256*8)), blk, 0, stream>>>(xr, conv_state, dones, conv_w, conv_b, xc);
  // 4. xdb = xc @ W_xproj^T (N=64, BK=64) -> fp32 (d_out scratch) + bf16 aux
  mgemm<6,float,256,64,64><<<dim3(M_/256, 1), blk, 0, stream>>>(xc, E_, wxp, E_, xdbf, 64, E_, nullptr, nullptr, xdb32);
  // 5. dt = softplus(xdb[:, :32] @ W_dt^T + b_dt)  -> fp16 (R0), K=32 -> BK=32
  mgemm<2,_Float16,128,128,32><<<dim3(M_/128, E_/128), blk, 0, stream>>>(xdb32, DR_, wdtb, DR_, dt, E_, DR_, b_dt, nullptr, nullptr);
  // 6. SSM scan (round-2 form, frozen) -> g over z (R1)
  scan_kernel<<<dim3(E_/256, B_), blk, 0, stream>>>(xc, xdbf, dt, zg, dones, ssm_state, A_log, Dv);
  // 7. h = g @ W_out^T + feats                     -> bf16 (R2), BK=64
  mgemm<3,u16,128,128,64><<<dim3(M_/128, H_/128), blk, 0, stream>>>(zg, E_, wout, E_, h, H_, E_, nullptr, feats, nullptr);
  // 8. h1 = relu(h @ W1^T + b1)                    -> bf16 (R0), BK=64
  mgemm<1,u16,128,128,64><<<dim3(M_/128, H_/128), blk, 0, stream>>>(h, H_, w1b, H_, h1, H_, H_, b1, nullptr, nullptr);
  // 9. h2 = h1 @ W2^T + b2                         -> d_out (fp32), BK=64
  mgemm<4,float,128,128,64><<<dim3(M_/128, H_/128), blk, 0, stream>>>(h1, H_, w2b, H_, out, H_, H_, b2, nullptr, nullptr);
  // 10. LayerNorm in-place on d_out
  ln_kernel<<<dim3(M_), blk, 0, stream>>>(out, gamma, beta);
}

// Round 10
// 675.053 us; speedup vs baseline: 1.0539x; 1.0539x over previous
//
#include <hip/hip_runtime.h>
#include <math.h>

// Problem constants
#define T_  256
#define B_  128
#define OBS_ 256
#define H_  512
#define E_  1024
#define DS_ 16
#define DC_ 4
#define DR_ 32
#define M_  (T_*B_)   // 32768 flattened (t,b) rows

typedef unsigned short u16;
typedef short short8 __attribute__((ext_vector_type(8)));   // 8 bf16 (4 VGPRs)
typedef unsigned short ushort8 __attribute__((ext_vector_type(8)));
typedef float f32x4  __attribute__((ext_vector_type(4)));

__device__ __forceinline__ float sigmoidf_(float v){ return 1.f/(1.f+__expf(-v)); }

__device__ __forceinline__ float b2f(u16 h){
  unsigned int x = ((unsigned int)h) << 16; float f;
  __builtin_memcpy(&f, &x, 4); return f;
}
__device__ __forceinline__ u16 f2b(float f){
  unsigned int x; __builtin_memcpy(&x, &f, 4);
  unsigned int lsb = (x >> 16) & 1u;
  x += 0x7fffu + lsb;            // RNE
  return (u16)(x >> 16);
}
__device__ __forceinline__ void ld4(const float* p, float v[4]){
  const float4 t = *(const float4*)p; v[0]=t.x; v[1]=t.y; v[2]=t.z; v[3]=t.w;
}
__device__ __forceinline__ void st4(u16* p, const float v[4]){
  ushort4 t; t.x=f2b(v[0]); t.y=f2b(v[1]); t.z=f2b(v[2]); t.w=f2b(v[3]);
  *(ushort4*)p = t;
}
__device__ __forceinline__ void store1(float* p, float v){ *p = v; }
__device__ __forceinline__ void store1(u16* p,  float v){ *p = f2b(v); }
__device__ __forceinline__ void store1(_Float16* p, float v){ *p = (_Float16)v; }

// async global->LDS, 16B per lane. LDS dest = wave-uniform base + lane*16.
__device__ __forceinline__ void gl_lds16(const u16* g, u16* l){
  __builtin_amdgcn_global_load_lds(
      (const __attribute__((address_space(1))) void*)g,
      (__attribute__((address_space(3))) void*)l, 16, 0, 0);
}

// All 7 weight tensors in one launch. Sizes in 1024-element chunks:
// enc 128 | in 1024 | xp 64 | out 512 | w1 256 | w2 256 | wdt 32 => 2272 blocks
__global__ __launch_bounds__(256) void cvt_weights(
    const float* __restrict__ w_enc, const float* __restrict__ w_in,
    const float* __restrict__ w_xp,  const float* __restrict__ w_out,
    const float* __restrict__ w1,    const float* __restrict__ w2,
    const float* __restrict__ w_dt,
    u16* o_enc, u16* o_in, u16* o_xp, u16* o_out, u16* o1, u16* o2, u16* o_dt)
{
  const int blk = blockIdx.x;
  const float* src; u16* dst; int base;
  if      (blk < 128)  { src=w_enc; dst=o_enc; base=blk; }
  else if (blk < 1152) { src=w_in;  dst=o_in;  base=blk-128; }
  else if (blk < 1216) { src=w_xp;  dst=o_xp;  base=blk-1152; }
  else if (blk < 1728) { src=w_out; dst=o_out; base=blk-1216; }
  else if (blk < 1984) { src=w1;    dst=o1;    base=blk-1728; }
  else if (blk < 2240) { src=w2;    dst=o2;    base=blk-1984; }
  else                 { src=w_dt;  dst=o_dt;  base=blk-2240; }
  const int i = base*1024 + threadIdx.x*4;
  float v[4]; ld4(src+i, v); st4(dst+i, v);
}

// ---------------------------------------------------------------------------
// MFMA bf16 GEMM (m97 structure, round-8 verified form): C = A @ B^T, BK=32,
// 256 thr = 4 waves, each wave 64x64 via 4x4 mfma_f32_16x16x32_bf16,
// global_load_lds staging. (Round-9 lesson: BK=64 regressed — fragment
// working set doubled; BK=32 is the validated point.)
// EP: 0 none, 1 bias+relu, 2 bias+softplus (fp16 out), 3 +bf16 residual,
//     4 bias only, 6 fp32 store + bf16 aux copy of cols<32
// ---------------------------------------------------------------------------
template<int EP, typename TC, int BM, int BN>
__global__ __launch_bounds__(256) void mgemm(
    const u16* __restrict__ A, int lda,
    const u16* __restrict__ Bm, int ldb,
    TC* __restrict__ C, int ldc, int K,
    const float* __restrict__ bias,
    const u16* __restrict__ add,
    u16* __restrict__ aux)
{
  constexpr int WC = BN/64;               // wave cols (BM/64 * BN/64 == 4)
  __shared__ __align__(16) u16 sm[(BM+BN)*32];
  u16* sA = sm;
  u16* sB = sm + BM*32;
  const int tid  = threadIdx.x;
  const int bm = blockIdx.x * BM, bn = blockIdx.y * BN;
  const int w = tid >> 6, lane = tid & 63;
  const int wr = (WC==1) ? w : (w >> 1);
  const int wc = (WC==1) ? 0 : (w & 1);
  const int ln = lane & 15, q = lane >> 4;

  const u16* Ag = A  + (size_t)(bm + (tid>>2))*lda + ((tid&3)<<3);
  const u16* Bg = Bm + (size_t)(bn + (tid>>2))*ldb + ((tid&3)<<3);
  const int arow = wr*64 + ln;
  const int brow = wc*64 + ln;

  f32x4 acc[4][4] = {};
  for (int k0 = 0; k0 < K; k0 += 32){
#pragma unroll
    for (int c = 0; c < BM/64; ++c)
      gl_lds16(Ag + (size_t)(c*64)*lda + k0, sA + c*2048 + tid*8);
#pragma unroll
    for (int c = 0; c < BN/64; ++c)
      gl_lds16(Bg + (size_t)(c*64)*ldb + k0, sB + c*2048 + tid*8);
    __syncthreads();
    short8 af[4], bf[4];
#pragma unroll
    for (int i=0;i<4;i++) af[i] = *(const short8*)&sA[(arow + i*16)*32 + q*8];
#pragma unroll
    for (int j=0;j<4;j++) bf[j] = *(const short8*)&sB[(brow + j*16)*32 + q*8];
#pragma unroll
    for (int i=0;i<4;i++)
#pragma unroll
      for (int j=0;j<4;j++)
        acc[i][j] = __builtin_amdgcn_mfma_f32_16x16x32_bf16(af[i], bf[j], acc[i][j], 0,0,0);
    __syncthreads();
  }
#pragma unroll
  for (int i=0;i<4;i++){
#pragma unroll
    for (int r=0;r<4;r++){
      const size_t row = (size_t)(bm + wr*64 + i*16 + q*4 + r);
#pragma unroll
      for (int j=0;j<4;j++){
        const int col = bn + wc*64 + j*16 + ln;
        float t = acc[i][j][r];
        if (EP==1 || EP==4) t += bias[col];
        if (EP==2){ t += bias[col];
                    t = fmaxf(t,0.f) + __logf(1.f + __expf(-fabsf(t))); }
        if (EP==1) t = fmaxf(t, 0.f);
        if (EP==3) t += b2f(add[row*(size_t)ldc + col]);
        store1(&C[row*(size_t)ldc + col], t);
        if (EP==6 && col < 32) aux[row*32 + col] = f2b(t);
      }
    }
  }
}

// ---------------------------------------------------------------------------
// Encoder GEMM with FUSED fp32->bf16 A-conversion: feats = relu(x @ Wenc^T
// + b_enc). Verified round 8; unchanged.
// ---------------------------------------------------------------------------
__global__ __launch_bounds__(256) void mgemm_enc(
    const float* __restrict__ A,        // fp32 [M][OBS]
    const u16* __restrict__ Bm,         // bf16 [H][OBS]
    u16* __restrict__ C,                // bf16 [M][H]
    const float* __restrict__ bias)
{
  __shared__ __align__(16) u16 sm[(128+128)*32];
  u16* sA = sm;
  u16* sB = sm + 128*32;
  const int tid  = threadIdx.x;
  const int bm = blockIdx.x * 128, bn = blockIdx.y * 128;
  const int w = tid >> 6, lane = tid & 63;
  const int wr = w >> 1, wc = w & 1;
  const int ln = lane & 15, q = lane >> 4;

  const float* Ag = A  + (size_t)(bm + (tid>>2))*OBS_ + ((tid&3)<<3);
  const u16*   Bg = Bm + (size_t)(bn + (tid>>2))*OBS_ + ((tid&3)<<3);
  const int arow = wr*64 + ln;
  const int brow = wc*64 + ln;

  f32x4 acc[4][4] = {};
  for (int k0 = 0; k0 < OBS_; k0 += 32){
#pragma unroll
    for (int c = 0; c < 2; ++c){
      const float* src = Ag + (size_t)(c*64)*OBS_ + k0;
      const float4 v0 = *(const float4*)(src);
      const float4 v1 = *(const float4*)(src + 4);
      ushort8 o;
      o[0]=f2b(v0.x); o[1]=f2b(v0.y); o[2]=f2b(v0.z); o[3]=f2b(v0.w);
      o[4]=f2b(v1.x); o[5]=f2b(v1.y); o[6]=f2b(v1.z); o[7]=f2b(v1.w);
      *(ushort8*)&sA[c*2048 + tid*8] = o;
    }
#pragma unroll
    for (int c = 0; c < 2; ++c)
      gl_lds16(Bg + (size_t)(c*64)*OBS_ + k0, sB + c*2048 + tid*8);
    __syncthreads();
    short8 af[4], bf[4];
#pragma unroll
    for (int i=0;i<4;i++) af[i] = *(const short8*)&sA[(arow + i*16)*32 + q*8];
#pragma unroll
    for (int j=0;j<4;j++) bf[j] = *(const short8*)&sB[(brow + j*16)*32 + q*8];
#pragma unroll
    for (int i=0;i<4;i++)
#pragma unroll
      for (int j=0;j<4;j++)
        acc[i][j] = __builtin_amdgcn_mfma_f32_16x16x32_bf16(af[i], bf[j], acc[i][j], 0,0,0);
    __syncthreads();
  }
#pragma unroll
  for (int i=0;i<4;i++){
#pragma unroll
    for (int r=0;r<4;r++){
      const size_t row = (size_t)(bm + wr*64 + i*16 + q*4 + r);
#pragma unroll
      for (int j=0;j<4;j++){
        const int col = bn + wc*64 + j*16 + ln;
        float t = acc[i][j][r] + bias[col];
        C[row*(size_t)H_ + col] = f2b(fmaxf(t, 0.f));
      }
    }
  }
}

// ---------------------------------------------------------------------------
// FUSED GEMM + LayerNorm: out = LN(h1 @ W2^T + b2) * gamma + beta, fp32.
// BM=128 x BN=512 (full rows) per block, 512 thr = 8 waves (2 wave-rows x
// 4 wave-cols, 64x128 per wave, acc[4][8]). LN stats in-epilogue: per-row
// j-sum -> 16-lane shfl_xor butterfly -> LDS [128][4] partials -> barrier ->
// mu/rstd -> normalized fp32 store. Kills the 64MB h2 write + 64MB LN read
// + ln_kernel dispatch.
// ---------------------------------------------------------------------------
__global__ __launch_bounds__(512, 2) void mgemm_ln(
    const u16* __restrict__ A,          // h1 [M][512] bf16
    const u16* __restrict__ Bm,         // W2 [512][512] bf16
    float* __restrict__ C,              // out [M][512] fp32
    const float* __restrict__ bias,     // b2
    const float* __restrict__ gamma, const float* __restrict__ beta)
{
  __shared__ __align__(16) u16 sA[128*32];
  __shared__ __align__(16) u16 sB[512*32];
  __shared__ float ssum[128][4];
  __shared__ float ssq[128][4];
  const int tid = threadIdx.x;
  const int bm = blockIdx.x * 128;
  const int w = tid >> 6, lane = tid & 63;
  const int wr = w >> 2;                // 0..1 (64-row band)
  const int wc = w & 3;                 // 0..3 (128-col band)
  const int ln = lane & 15, q = lane >> 4;

  const u16* Ag = A  + (size_t)(bm + (tid>>2))*H_ + ((tid&3)<<3);
  const u16* Bg = Bm + (size_t)(tid>>2)*H_ + ((tid&3)<<3);
  const int arow = wr*64 + ln;
  const int brow = wc*128 + ln;

  f32x4 acc[4][8] = {};
  for (int k0 = 0; k0 < H_; k0 += 32){
    gl_lds16(Ag + k0, sA + tid*8);      // 512 thr x 8 = 128x32 in one call
#pragma unroll
    for (int c = 0; c < 4; ++c)         // B: 4 x 128 rows
      gl_lds16(Bg + (size_t)(c*128)*H_ + k0, sB + c*4096 + tid*8);
    __syncthreads();
    short8 af[4], bf[8];
#pragma unroll
    for (int i=0;i<4;i++) af[i] = *(const short8*)&sA[(arow + i*16)*32 + q*8];
#pragma unroll
    for (int j=0;j<8;j++) bf[j] = *(const short8*)&sB[(brow + j*16)*32 + q*8];
#pragma unroll
    for (int i=0;i<4;i++)
#pragma unroll
      for (int j=0;j<8;j++)
        acc[i][j] = __builtin_amdgcn_mfma_f32_16x16x32_bf16(af[i], bf[j], acc[i][j], 0,0,0);
    __syncthreads();
  }

  // epilogue: bias, then per-row stats
  float bb[8], gj[8], bj[8];
#pragma unroll
  for (int j=0;j<8;j++){
    const int col = wc*128 + j*16 + ln;
    bb[j] = bias[col]; gj[j] = gamma[col]; bj[j] = beta[col];
  }
#pragma unroll
  for (int i=0;i<4;i++)
#pragma unroll
    for (int j=0;j<8;j++)
#pragma unroll
      for (int r=0;r<4;r++) acc[i][j][r] += bb[j];

#pragma unroll
  for (int i=0;i<4;i++){
#pragma unroll
    for (int r=0;r<4;r++){
      float s = 0.f, s2 = 0.f;
#pragma unroll
      for (int j=0;j<8;j++){ const float v = acc[i][j][r]; s += v; s2 = fmaf(v,v,s2); }
#pragma unroll
      for (int m=1;m<=8;m<<=1){ s += __shfl_xor(s,m); s2 += __shfl_xor(s2,m); }
      if (ln == 0){
        const int lrow = wr*64 + i*16 + q*4 + r;
        ssum[lrow][wc] = s; ssq[lrow][wc] = s2;
      }
    }
  }
  __syncthreads();
#pragma unroll
  for (int i=0;i<4;i++){
#pragma unroll
    for (int r=0;r<4;r++){
      const int lrow = wr*64 + i*16 + q*4 + r;
      const float st = ssum[lrow][0]+ssum[lrow][1]+ssum[lrow][2]+ssum[lrow][3];
      const float qt = ssq[lrow][0]+ssq[lrow][1]+ssq[lrow][2]+ssq[lrow][3];
      const float mu = st * (1.f/H_);
      const float var = qt * (1.f/H_) - mu*mu;
      const float rstd = rsqrtf(var + 1e-5f);
      const size_t row = (size_t)(bm + lrow);
#pragma unroll
      for (int j=0;j<8;j++){
        const int col = wc*128 + j*16 + ln;
        C[row*H_ + col] = (acc[i][j][r] - mu) * rstd * gj[j] + bj[j];
      }
    }
  }
}

// xc[t,b,e] = silu( sum_j conv_w[e,j] * masked_src(t-3+j) + conv_b[e] )
// Vectorized x8 (G13); block is t-uniform. Verified rounds 7-9; unchanged.
__global__ __launch_bounds__(256) void conv_kernel(
    const u16* __restrict__ xr, const float* __restrict__ conv_state,
    const int* __restrict__ dones,
    const float* __restrict__ conv_w, const float* __restrict__ conv_b,
    u16* __restrict__ xc)
{
  const int g = blockIdx.x * 256 + threadIdx.x;   // over T*B*E/8
  const int e8   = g & 127;                       // E_/8 = 128
  const int rest = g >> 7;
  const int b = rest & (B_-1);
  const int t = rest >> 7;
  const int e0 = e8 * 8;

  float wv[8][4];
#pragma unroll
  for (int j=0;j<8;j++) ld4(conv_w + (e0+j)*4, wv[j]);
  float bias[8];
  { float v[4]; ld4(conv_b + e0,     v); bias[0]=v[0];bias[1]=v[1];bias[2]=v[2];bias[3]=v[3];
    ld4(conv_b + e0 + 4, v); bias[4]=v[0];bias[5]=v[1];bias[6]=v[2];bias[7]=v[3]; }

  float csv[8][4];
  if (t < 3){
#pragma unroll
    for (int j=0;j<8;j++) ld4(conv_state + ((size_t)(b*E_+e0+j))*4, csv[j]);
  }

  const size_t row = ((size_t)(t*B_+b))*E_ + e0;
  const ushort8 x3 = *(const ushort8*)&xr[row];
  float val[8];
#pragma unroll
  for (int j=0;j<8;j++) val[j] = wv[j][3] * b2f(x3[j]);

  float m = 1.f;
  if (t >= 1){
    m *= 1.f - (float)dones[(t-1)*B_+b];
    const ushort8 xv = *(const ushort8*)&xr[row - (size_t)B_*E_];
#pragma unroll
    for (int j=0;j<8;j++) val[j] = fmaf(wv[j][2], m*b2f(xv[j]), val[j]);
  } else {
#pragma unroll
    for (int j=0;j<8;j++) val[j] = fmaf(wv[j][2], csv[j][3], val[j]);
  }
  if (t >= 2){
    m *= 1.f - (float)dones[(t-2)*B_+b];
    const ushort8 xv = *(const ushort8*)&xr[row - (size_t)2*B_*E_];
#pragma unroll
    for (int j=0;j<8;j++) val[j] = fmaf(wv[j][1], m*b2f(xv[j]), val[j]);
  } else {
#pragma unroll
    for (int j=0;j<8;j++) val[j] = fmaf(wv[j][1], m*csv[j][t-2+4], val[j]);
  }
  if (t >= 3){
    m *= 1.f - (float)dones[(t-3)*B_+b];
    const ushort8 xv = *(const ushort8*)&xr[row - (size_t)3*B_*E_];
#pragma unroll
    for (int j=0;j<8;j++) val[j] = fmaf(wv[j][0], m*b2f(xv[j]), val[j]);
  } else {
#pragma unroll
    for (int j=0;j<8;j++) val[j] = fmaf(wv[j][0], m*csv[j][t-3+4], val[j]);
  }

  ushort8 o;
#pragma unroll
  for (int j=0;j<8;j++){
    const float v = val[j] + bias[j];
    o[j] = f2b(v * sigmoidf_(v));   // silu
  }
  *(ushort8*)&xc[((size_t)(t*B_+b))*E_ + e0] = o;
}

// ---------------------------------------------------------------------------
// SSM scan (round-2 form, FROZEN — rounds 3-7 all regressed perturbations).
// Byte-identical to the verified 116.8-us configuration.
// ---------------------------------------------------------------------------
template<bool ST>
__device__ __forceinline__ void scan_loop(
    const float4* rp, const _Float16* dtp, const u16* xcp, u16* zp,
    const int* dp, float* s, const float* Ae, float c, float Dv)
{
  float mprev = 1.f;
#pragma unroll 2
  for (int t=0;t<T_;t++){
    float4 r[8];
#pragma unroll
    for (int i=0;i<8;i++) r[i] = rp[i];
    const float dtv = (float)dtp[0];
    const float xcv = b2f(*xcp);
    const float zv  = b2f(*zp);
    const int   dn  = *dp;

    float Bv[16], Cv[16];
#pragma unroll
    for (int i=0;i<4;i++){
      Bv[4*i+0]=r[i].x;   Bv[4*i+1]=r[i].y;   Bv[4*i+2]=r[i].z;   Bv[4*i+3]=r[i].w;
      Cv[4*i+0]=r[4+i].x; Cv[4*i+1]=r[4+i].y; Cv[4*i+2]=r[4+i].z; Cv[4*i+3]=r[4+i].w;
    }
    const float xdt = xcv * dtv;

    float p[16];
    if (ST){
      // dA[n] = q^(n+1), q = exp(dtv*A[e,0]); carry-mask folded into q.
      const float q = __expf(dtv * c) * mprev;
      const float q2 = q*q;
      const float q4 = q2*q2;
      const float q8 = q4*q4;
      p[0]=q;     p[1]=q2;    p[2]=q2*q;  p[3]=q4;
      p[4]=q4*q;  p[5]=q4*q2; p[6]=q4*p[2]; p[7]=q8;
      p[8]=q8*q;  p[9]=q8*q2; p[10]=q8*p[2]; p[11]=q8*q4;
      p[12]=q8*p[4]; p[13]=q8*p[5]; p[14]=q8*p[6]; p[15]=q8*q8;
    } else {
#pragma unroll
      for (int n=0;n<DS_;n++) p[n] = __expf(dtv * Ae[n]) * mprev;
    }

    float y0 = Dv * xcv, y1 = 0.f;
#pragma unroll
    for (int n=0;n<DS_;n++){
      s[n] = fmaf(s[n], p[n], xdt * Bv[n]);
      if (n & 1) y1 = fmaf(s[n], Cv[n], y1);
      else       y0 = fmaf(s[n], Cv[n], y0);
    }
    mprev = dn ? 0.f : 1.f;
    *zp = f2b((y0+y1) * zv * sigmoidf_(zv));     // g = y * silu(z)

    rp  += (size_t)B_*16;          // xdb rows are 16 float4 wide
    dtp += (size_t)B_*E_;
    xcp += (size_t)B_*E_;
    zp  += (size_t)B_*E_;
    dp  += B_;
  }
}

__global__ __launch_bounds__(256, 2) void scan_kernel(
    const u16* __restrict__ xc, const float* __restrict__ xdb,
    const _Float16* __restrict__ dt,
    u16* __restrict__ zg,
    const int* __restrict__ dones,
    const float* __restrict__ ssm_state, const float* __restrict__ A_log,
    const float* __restrict__ Dvec)
{
  const int e = blockIdx.x * 256 + threadIdx.x;  // grid.x = E_/256
  const int b = blockIdx.y;
  float Ae[DS_], s[DS_];
#pragma unroll
  for (int n=0;n<DS_;n++){
    Ae[n] = -expf(A_log[e*DS_+n]);
    s[n]  = ssm_state[((size_t)(b*E_+e))*DS_ + n];
  }
  const float c = Ae[0];
  bool st = true;
#pragma unroll
  for (int n=1;n<DS_;n++)
    st = st && (fabsf(Ae[n] - (float)(n+1)*c) <= 1e-5f*(float)(n+1)*fabsf(c));
  const float Dv = Dvec[e];

  const float4*    rp  = (const float4*)xdb + (size_t)b*16 + 8;  // cols 32..63
  const _Float16*  dtp = dt + (size_t)b*E_ + e;
  const u16*       xcp = xc + (size_t)b*E_ + e;
  u16*             zp  = zg + (size_t)b*E_ + e;
  const int*       dp  = dones + b;

  if (st) scan_loop<true >(rp, dtp, xcp, zp, dp, s, Ae, c, Dv);
  else    scan_loop<false>(rp, dtp, xcp, zp, dp, s, Ae, c, Dv);
}

extern "C" void kernel_launch(void* const* d_in, const int* in_sizes, int n_in,
                              void* d_out, int out_size, void* d_ws, size_t ws_size,
                              hipStream_t stream)
{
  const float* x          = (const float*)d_in[0];
  const int*   dones      = (const int*)  d_in[1];
  const float* conv_state = (const float*)d_in[2];
  const float* ssm_state  = (const float*)d_in[3];
  const float* W_enc      = (const float*)d_in[4];
  const float* b_enc      = (const float*)d_in[5];
  const float* W_in       = (const float*)d_in[6];
  const float* conv_w     = (const float*)d_in[7];
  const float* conv_b     = (const float*)d_in[8];
  const float* W_xproj    = (const float*)d_in[9];
  const float* W_dt       = (const float*)d_in[10];
  const float* b_dt       = (const float*)d_in[11];
  const float* A_log      = (const float*)d_in[12];
  const float* Dv         = (const float*)d_in[13];
  const float* W_out      = (const float*)d_in[14];
  const float* W1         = (const float*)d_in[15];
  const float* b1         = (const float*)d_in[16];
  const float* W2         = (const float*)d_in[17];
  const float* b2         = (const float*)d_in[18];
  const float* gamma      = (const float*)d_in[19];
  const float* beta       = (const float*)d_in[20];

  // Workspace layout IDENTICAL to known-good 205,914,112-byte footprint
  // (round-8 configuration):
  //  R0: xr bf16 (step 2-3) -> dt fp16 (5-6) -> h1 bf16 (8-9)
  //  R1: z bf16 (2-6) -> g (6-7)
  //  R2: xc (3-6) -> h bf16 (7-8)
  //  d_out (64 MiB): feats bf16 [0,32Mi) (1-7); xdb f32 @32Mi (4-6);
  //    xdb32 bf16 @40Mi (4-5); wdtb bf16 @44Mi (0-5); out fp32 (9, fused LN)
  char* w = (char*)d_ws;
  u16*   xr   = (u16*)(w + 0);
  _Float16* dt = (_Float16*)(w + 0);
  u16*   h1   = (u16*)(w + 0);
  u16*   zg   = (u16*)(w + 67108864);
  u16*   xc   = (u16*)(w + 134217728);
  u16*   h    = (u16*)(w + 134217728);
  u16*   wenc = (u16*)(w + 201326592);
  u16*   win  = wenc + 131072;
  u16*   wxp  = win  + 1048576;
  u16*   wout = wxp  + 65536;
  u16*   w1b  = wout + 524288;
  u16*   w2b  = w1b  + 262144;
  u16*   feats = (u16*)d_out;
  float* xdbf  = (float*)((char*)d_out + 33554432);   // M x 64 fp32 (8.4 MB)
  u16*   xdb32 = (u16*)  ((char*)d_out + 41943040);   // M x 32 bf16 (2.1 MB)
  u16*   wdtb  = (u16*)  ((char*)d_out + 46137344);   // E x 32 bf16 (64 KiB)
  float* out   = (float*)d_out;

  const dim3 blk(256);

  // 0. weight fp32 -> bf16 conversion
  cvt_weights<<<dim3(2272), blk, 0, stream>>>(W_enc, W_in, W_xproj, W_out, W1, W2, W_dt,
                                              wenc, win, wxp, wout, w1b, w2b, wdtb);

  // 1. feats = relu(x @ W_enc^T + b_enc), fused fp32->bf16 A-staging -> d_out
  mgemm_enc<<<dim3(M_/128, H_/128), blk, 0, stream>>>(x, wenc, feats, b_enc);
  // 2a. xr = feats @ W_in[:E]^T                    -> R0 (bf16)
  mgemm<0,u16,128,128><<<dim3(M_/128, E_/128), blk, 0, stream>>>(feats, H_, win, H_, xr, E_, H_, nullptr, nullptr, nullptr);
  // 2b. z = feats @ W_in[E:]^T                     -> R1 (bf16)
  mgemm<0,u16,128,128><<<dim3(M_/128, E_/128), blk, 0, stream>>>(feats, H_, win + (size_t)E_*H_, H_, zg, E_, H_, nullptr, nullptr, nullptr);
  // 3. masked causal conv + silu                   -> xc (bf16, R2)
  conv_kernel<<<dim3((M_*E_)/(256*8)), blk, 0, stream>>>(xr, conv_state, dones, conv_w, conv_b, xc);
  // 4. xdb = xc @ W_xproj^T (N=64) -> fp32 (d_out scratch) + bf16 cols<32 aux
  mgemm<6,float,256,64><<<dim3(M_/256, 1), blk, 0, stream>>>(xc, E_, wxp, E_, xdbf, 64, E_, nullptr, nullptr, xdb32);
  // 5. dt = softplus(xdb[:, :32] @ W_dt^T + b_dt)  -> fp16 (R0), MFMA
  mgemm<2,_Float16,128,128><<<dim3(M_/128, E_/128), blk, 0, stream>>>(xdb32, DR_, wdtb, DR_, dt, E_, DR_, b_dt, nullptr, nullptr);
  // 6. SSM scan (round-2 form, frozen) -> g over z (R1)
  scan_kernel<<<dim3(E_/256, B_), blk, 0, stream>>>(xc, xdbf, dt, zg, dones, ssm_state, A_log, Dv);
  // 7. h = g @ W_out^T + feats                     -> bf16 (R2)
  mgemm<3,u16,128,128><<<dim3(M_/128, H_/128), blk, 0, stream>>>(zg, E_, wout, E_, h, H_, E_, nullptr, feats, nullptr);
  // 8. h1 = relu(h @ W1^T + b1)                    -> bf16 (R0)
  mgemm<1,u16,128,128><<<dim3(M_/128, H_/128), blk, 0, stream>>>(h, H_, w1b, H_, h1, H_, H_, b1, nullptr, nullptr);
  // 9. out = LN(h1 @ W2^T + b2) * gamma + beta     -> d_out (fp32, fused)
  mgemm_ln<<<dim3(M_/128), dim3(512), 0, stream>>>(h1, w2b, out, b2, gamma, beta);
}